// Round 5
// baseline (390.874 us; speedup 1.0000x reference)
//
#include <hip/hip_runtime.h>

constexpr int NN    = 100000;   // nodes
constexpr int NNZ_E = 1600000;  // sparse entries
constexpr int EQn   = 200000;   // edges to score
constexpr int INF_  = 256;
constexpr int HIDF  = 128;
constexpr int OUTF  = 64;

typedef float  f32x4  __attribute__((ext_vector_type(4)));
typedef short  bf16x8 __attribute__((ext_vector_type(8)));

// fp32 -> bf16 (round to nearest even)
__device__ inline unsigned short f2bf(float f) {
    union { float f; unsigned int i; } x; x.f = f;
    unsigned int r = x.i + 0x7fffu + ((x.i >> 16) & 1u);
    return (unsigned short)(r >> 16);
}

// ---------------------------------------------------------------------------
// CSR row_ptr from sorted rows: ptr[i] = lower_bound(rows, i)
// ---------------------------------------------------------------------------
__global__ __launch_bounds__(256) void build_row_ptr(const int* __restrict__ rows,
                                                     int* __restrict__ ptr) {
    int i = blockIdx.x * 256 + threadIdx.x;
    if (i > NN) return;
    int lo = 0, hi = NNZ_E;
    while (lo < hi) {
        int mid = (lo + hi) >> 1;
        if (rows[mid] < i) lo = mid + 1; else hi = mid;
    }
    ptr[i] = lo;
}

// ---------------------------------------------------------------------------
// One-shot: W[k][n] fp32 -> Wt[n][k] bf16 for both layers (tiny).
// ---------------------------------------------------------------------------
__global__ __launch_bounds__(256) void convert_weights(const float* __restrict__ W1,
                                                       const float* __restrict__ W2,
                                                       unsigned short* __restrict__ W1t,
                                                       unsigned short* __restrict__ W2t) {
    int i = blockIdx.x * 256 + threadIdx.x;
    if (i < INF_ * HIDF) {            // W1 [256][128]
        int k = i >> 7, n = i & 127;
        W1t[n * INF_ + k] = f2bf(W1[i]);
    }
    if (i < HIDF * OUTF) {            // W2 [128][64]
        int k = i >> 6, n = i & 63;
        W2t[n * HIDF + k] = f2bf(W2[i]);
    }
}

// ---------------------------------------------------------------------------
// Barrier-free MFMA GEMM with HOISTED A-loads:
//   C_bf16[M,NCOLS] = A[M,K] @ Wt_bf16[NCOLS][K] + bias
// A is fp32 (A_IS_BF16=false) or bf16 (true). All KS k-steps' A-loads are
// issued before the MFMA sequence -> KS(*2) independent global loads in
// flight per wave (the round-4 version kept ~2 and was latency-serialized).
// B fragments load direct from Wt (L1/L2-hot, 64 B per row per step).
// Epilogue staged through LDS for coalesced 16 B stores.
// ---------------------------------------------------------------------------
template<int K, int NCOLS, bool A_IS_BF16>
__global__ __launch_bounds__(256) void gemm_direct(const void* __restrict__ Av,
                                                   const unsigned short* __restrict__ Bt,
                                                   const float* __restrict__ bias,
                                                   unsigned short* __restrict__ C,
                                                   int M) {
    constexpr int NT   = NCOLS / 16;   // 16x16 tiles per wave (cols)
    constexpr int KS   = K / 32;       // k-steps
    constexpr int PADW = NCOLS + 8;
    __shared__ unsigned short cst[4 * 16 * PADW];

    const int tid  = threadIdx.x;
    const int wave = tid >> 6;
    const int lane = tid & 63;
    const int quad = lane >> 4;
    const int l16  = lane & 15;
    const int row0w = blockIdx.x * 64 + wave * 16;

    int arow = row0w + l16; if (arow > M - 1) arow = M - 1;   // clamp; tail unused

    f32x4 acc[NT];
    #pragma unroll
    for (int t = 0; t < NT; ++t) acc[t] = (f32x4){0.f, 0.f, 0.f, 0.f};

    // ---- hoist ALL A loads (independent, stay in flight together) ----
    bf16x8 afrag[KS];
    if constexpr (A_IS_BF16) {
        const unsigned short* ap = (const unsigned short*)Av + (size_t)arow * K + quad * 8;
        #pragma unroll
        for (int ks = 0; ks < KS; ++ks)
            afrag[ks] = *(const bf16x8*)(ap + ks * 32);
    } else {
        const float* ap = (const float*)Av + (size_t)arow * K + quad * 8;
        float4 a0[KS], a1[KS];
        #pragma unroll
        for (int ks = 0; ks < KS; ++ks) {
            a0[ks] = *(const float4*)(ap + ks * 32);
            a1[ks] = *(const float4*)(ap + ks * 32 + 4);
        }
        #pragma unroll
        for (int ks = 0; ks < KS; ++ks) {
            afrag[ks][0] = (short)f2bf(a0[ks].x); afrag[ks][1] = (short)f2bf(a0[ks].y);
            afrag[ks][2] = (short)f2bf(a0[ks].z); afrag[ks][3] = (short)f2bf(a0[ks].w);
            afrag[ks][4] = (short)f2bf(a1[ks].x); afrag[ks][5] = (short)f2bf(a1[ks].y);
            afrag[ks][6] = (short)f2bf(a1[ks].z); afrag[ks][7] = (short)f2bf(a1[ks].w);
        }
    }

    const unsigned short* bp = &Bt[(size_t)l16 * K + quad * 8];
    #pragma unroll
    for (int ks = 0; ks < KS; ++ks) {
        #pragma unroll
        for (int t = 0; t < NT; ++t) {
            bf16x8 bf = *(const bf16x8*)(bp + (size_t)t * 16 * K + ks * 32);
            acc[t] = __builtin_amdgcn_mfma_f32_16x16x32_bf16(afrag[ks], bf, acc[t], 0, 0, 0);
        }
    }

    // ---- epilogue: C/D layout col=lane&15, row=quad*4+reg ----
    unsigned short* my = &cst[wave * 16 * PADW];
    #pragma unroll
    for (int t = 0; t < NT; ++t) {
        const float bb = bias[t * 16 + l16];
        #pragma unroll
        for (int r = 0; r < 4; ++r)
            my[(quad * 4 + r) * PADW + t * 16 + l16] = f2bf(acc[t][r] + bb);
    }
    __syncthreads();
    constexpr int CH = NCOLS / 8;          // 16B chunks per row
    #pragma unroll
    for (int i = 0; i < CH / 4; ++i) {
        int id = i * 64 + lane;
        int r  = id / CH, cc = id % CH;
        int grow = row0w - wave * 16 + (wave * 16 + r);   // = block row base + r within wave band
        grow = blockIdx.x * 64 + wave * 16 + r;
        if (grow < M)
            *(uint4*)&C[(size_t)grow * NCOLS + cc * 8] =
                *(const uint4*)&my[r * PADW + cc * 8];
    }
}

// ---------------------------------------------------------------------------
// Row-parallel CSR SpMM, bf16 table -> bf16 output, fp32 accumulate.
// Cooperative edge staging: the LPR lanes of a row-group load LPR cols/vals
// coalesced, broadcast via __shfl(width=LPR) -> LPR independent gathers in
// flight, no redundant scalar loads.
// ---------------------------------------------------------------------------
template<int D, bool RELU>
__global__ __launch_bounds__(256) void spmm_bf16(const int* __restrict__ ptr,
                                                 const int* __restrict__ cols,
                                                 const float* __restrict__ vals,
                                                 const unsigned short* __restrict__ dense,
                                                 unsigned short* __restrict__ outm) {
    constexpr int LPR = D / 8;       // lanes per row
    constexpr int RPB = 256 / LPR;   // rows per block
    const int lane = threadIdx.x % LPR;
    const int row  = blockIdx.x * RPB + threadIdx.x / LPR;
    if (row >= NN) return;

    int e = ptr[row];
    const int e1 = ptr[row + 1];
    float acc[8] = {};
    union { unsigned int i; float f; } t;

    for (; e + LPR <= e1; e += LPR) {
        int   myc = cols[e + lane];
        float myv = vals[e + lane];
        #pragma unroll
        for (int j = 0; j < LPR; ++j) {
            int   c = __shfl(myc, j, LPR);
            float v = __shfl(myv, j, LPR);
            uint4 q = *(const uint4*)&dense[(size_t)c * D + lane * 8];
            #pragma unroll
            for (int p = 0; p < 4; ++p) {
                unsigned int w = (&q.x)[p];
                t.i = w << 16;          acc[2*p]   += v * t.f;
                t.i = w & 0xffff0000u;  acc[2*p+1] += v * t.f;
            }
        }
    }
    for (; e < e1; ++e) {
        int   c = cols[e];
        float v = vals[e];
        uint4 q = *(const uint4*)&dense[(size_t)c * D + lane * 8];
        #pragma unroll
        for (int p = 0; p < 4; ++p) {
            unsigned int w = (&q.x)[p];
            t.i = w << 16;          acc[2*p]   += v * t.f;
            t.i = w & 0xffff0000u;  acc[2*p+1] += v * t.f;
        }
    }

    if (RELU) {
        #pragma unroll
        for (int p = 0; p < 8; ++p) acc[p] = fmaxf(acc[p], 0.f);
    }
    uint4 o;
    #pragma unroll
    for (int p = 0; p < 4; ++p)
        (&o.x)[p] = (unsigned int)f2bf(acc[2*p]) | ((unsigned int)f2bf(acc[2*p+1]) << 16);
    *(uint4*)&outm[(size_t)row * D + lane * 8] = o;
}

// ---------------------------------------------------------------------------
// Decode: out[e] = dot(z[src[e]], z[dst[e]]), z bf16 [N,64]. 8 lanes/edge.
// ---------------------------------------------------------------------------
__global__ __launch_bounds__(256) void decode_dot_bf16(const unsigned short* __restrict__ z,
                                                       const int* __restrict__ ei,
                                                       float* __restrict__ outv) {
    const int lane = threadIdx.x & 7;
    const int e    = blockIdx.x * 32 + (threadIdx.x >> 3);
    if (e >= EQn) return;
    const int s = ei[e];
    const int d = ei[EQn + e];
    uint4 qa = *(const uint4*)&z[(size_t)s * 64 + lane * 8];
    uint4 qb = *(const uint4*)&z[(size_t)d * 64 + lane * 8];
    union { unsigned int i; float f; } ta, tb;
    float p = 0.f;
    #pragma unroll
    for (int k = 0; k < 4; ++k) {
        unsigned int wa = (&qa.x)[k], wb = (&qb.x)[k];
        ta.i = wa << 16;         tb.i = wb << 16;         p += ta.f * tb.f;
        ta.i = wa & 0xffff0000u; tb.i = wb & 0xffff0000u; p += ta.f * tb.f;
    }
    p += __shfl_xor(p, 1, 8);
    p += __shfl_xor(p, 2, 8);
    p += __shfl_xor(p, 4, 8);
    if (lane == 0) outv[e] = p;
}

// ---------------------------------------------------------------------------
extern "C" void kernel_launch(void* const* d_in, const int* in_sizes, int n_in,
                              void* d_out, int out_size, void* d_ws, size_t ws_size,
                              hipStream_t stream) {
    (void)in_sizes; (void)n_in; (void)out_size; (void)ws_size;

    const float* x        = (const float*)d_in[0];
    const int*   adj_rows = (const int*)  d_in[1];
    const int*   adj_cols = (const int*)  d_in[2];
    const float* adj_vals = (const float*)d_in[3];
    const int*   ei       = (const int*)  d_in[4];   // [2, EQ]
    const float* W1       = (const float*)d_in[5];
    const float* b1       = (const float*)d_in[6];
    const float* W2       = (const float*)d_in[7];
    const float* b2       = (const float*)d_in[8];
    float* out = (float*)d_out;

    // workspace: row_ptr | W1t | W2t | slotA bf16 [N,128] | slotB bf16 [N,128]
    char* ws = (char*)d_ws;
    int* row_ptr = (int*)ws;
    size_t off = ((size_t)(NN + 1) * sizeof(int) + 511) & ~(size_t)511;
    unsigned short* W1t = (unsigned short*)(ws + off);              // 64 KB
    unsigned short* W2t = W1t + (size_t)HIDF * INF_;                // 16 KB
    unsigned short* slotA = W2t + (size_t)OUTF * HIDF;
    slotA = (unsigned short*)(((size_t)slotA + 511) & ~(size_t)511);
    unsigned short* slotB = slotA + (size_t)NN * HIDF;

    build_row_ptr<<<(NN + 256) / 256, 256, 0, stream>>>(adj_rows, row_ptr);
    convert_weights<<<(INF_ * HIDF + 255) / 256, 256, 0, stream>>>(W1, W2, W1t, W2t);

    // h0 = x @ W1 + b1  -> slotA bf16 [N,128]
    gemm_direct<INF_, HIDF, false><<<(NN + 63) / 64, 256, 0, stream>>>(
        x, W1t, b1, slotA, NN);

    // h = relu(spmm(h0)) -> slotB bf16 [N,128]
    spmm_bf16<HIDF, true><<<(NN + 15) / 16, 256, 0, stream>>>(
        row_ptr, adj_cols, adj_vals, slotA, slotB);

    // z0 = h @ W2 + b2 -> slotA bf16 [N,64]  (A is bf16 now)
    gemm_direct<HIDF, OUTF, true><<<(NN + 63) / 64, 256, 0, stream>>>(
        slotB, W2t, b2, slotA, NN);

    // z = spmm(z0) -> slotB bf16 [N,64]
    spmm_bf16<OUTF, false><<<(NN + 31) / 32, 256, 0, stream>>>(
        row_ptr, adj_cols, adj_vals, slotA, slotB);

    // out[e] = dot(z[src], z[dst])
    decode_dot_bf16<<<EQn / 32, 256, 0, stream>>>(slotB, ei, out);
}

// Round 6
// 332.276 us; speedup vs baseline: 1.1764x; 1.1764x over previous
//
#include <hip/hip_runtime.h>

constexpr int NN    = 100000;   // nodes
constexpr int NNZ_E = 1600000;  // sparse entries
constexpr int EQn   = 200000;   // edges to score
constexpr int INF_  = 256;
constexpr int HIDF  = 128;
constexpr int OUTF  = 64;

typedef float  f32x4  __attribute__((ext_vector_type(4)));
typedef short  bf16x8 __attribute__((ext_vector_type(8)));

// fp32 -> bf16 (round to nearest even)
__device__ inline unsigned short f2bf(float f) {
    union { float f; unsigned int i; } x; x.f = f;
    unsigned int r = x.i + 0x7fffu + ((x.i >> 16) & 1u);
    return (unsigned short)(r >> 16);
}

// ---------------------------------------------------------------------------
// CSR row_ptr from sorted rows: ptr[i] = lower_bound(rows, i)
// ---------------------------------------------------------------------------
__global__ __launch_bounds__(256) void build_row_ptr(const int* __restrict__ rows,
                                                     int* __restrict__ ptr) {
    int i = blockIdx.x * 256 + threadIdx.x;
    if (i > NN) return;
    int lo = 0, hi = NNZ_E;
    while (lo < hi) {
        int mid = (lo + hi) >> 1;
        if (rows[mid] < i) lo = mid + 1; else hi = mid;
    }
    ptr[i] = lo;
}

// ---------------------------------------------------------------------------
// One-shot: W[k][n] fp32 -> Wt[n][k] bf16 for both layers (tiny).
// ---------------------------------------------------------------------------
__global__ __launch_bounds__(256) void convert_weights(const float* __restrict__ W1,
                                                       const float* __restrict__ W2,
                                                       unsigned short* __restrict__ W1t,
                                                       unsigned short* __restrict__ W2t) {
    int i = blockIdx.x * 256 + threadIdx.x;
    if (i < INF_ * HIDF) {            // W1 [256][128]
        int k = i >> 7, n = i & 127;
        W1t[n * INF_ + k] = f2bf(W1[i]);
    }
    if (i < HIDF * OUTF) {            // W2 [128][64]
        int k = i >> 6, n = i & 63;
        W2t[n * HIDF + k] = f2bf(W2[i]);
    }
}

// ---------------------------------------------------------------------------
// Barrier-free MFMA GEMM with hoisted A-loads (unchanged from round 5).
// ---------------------------------------------------------------------------
template<int K, int NCOLS, bool A_IS_BF16>
__global__ __launch_bounds__(256) void gemm_direct(const void* __restrict__ Av,
                                                   const unsigned short* __restrict__ Bt,
                                                   const float* __restrict__ bias,
                                                   unsigned short* __restrict__ C,
                                                   int M) {
    constexpr int NT   = NCOLS / 16;   // 16x16 tiles per wave (cols)
    constexpr int KS   = K / 32;       // k-steps
    constexpr int PADW = NCOLS + 8;
    __shared__ unsigned short cst[4 * 16 * PADW];

    const int tid  = threadIdx.x;
    const int wave = tid >> 6;
    const int lane = tid & 63;
    const int quad = lane >> 4;
    const int l16  = lane & 15;
    const int row0w = blockIdx.x * 64 + wave * 16;

    int arow = row0w + l16; if (arow > M - 1) arow = M - 1;   // clamp; tail unused

    f32x4 acc[NT];
    #pragma unroll
    for (int t = 0; t < NT; ++t) acc[t] = (f32x4){0.f, 0.f, 0.f, 0.f};

    // ---- hoist ALL A loads (independent, stay in flight together) ----
    bf16x8 afrag[KS];
    if constexpr (A_IS_BF16) {
        const unsigned short* ap = (const unsigned short*)Av + (size_t)arow * K + quad * 8;
        #pragma unroll
        for (int ks = 0; ks < KS; ++ks)
            afrag[ks] = *(const bf16x8*)(ap + ks * 32);
    } else {
        const float* ap = (const float*)Av + (size_t)arow * K + quad * 8;
        float4 a0[KS], a1[KS];
        #pragma unroll
        for (int ks = 0; ks < KS; ++ks) {
            a0[ks] = *(const float4*)(ap + ks * 32);
            a1[ks] = *(const float4*)(ap + ks * 32 + 4);
        }
        #pragma unroll
        for (int ks = 0; ks < KS; ++ks) {
            afrag[ks][0] = (short)f2bf(a0[ks].x); afrag[ks][1] = (short)f2bf(a0[ks].y);
            afrag[ks][2] = (short)f2bf(a0[ks].z); afrag[ks][3] = (short)f2bf(a0[ks].w);
            afrag[ks][4] = (short)f2bf(a1[ks].x); afrag[ks][5] = (short)f2bf(a1[ks].y);
            afrag[ks][6] = (short)f2bf(a1[ks].z); afrag[ks][7] = (short)f2bf(a1[ks].w);
        }
    }

    const unsigned short* bp = &Bt[(size_t)l16 * K + quad * 8];
    #pragma unroll
    for (int ks = 0; ks < KS; ++ks) {
        #pragma unroll
        for (int t = 0; t < NT; ++t) {
            bf16x8 bf = *(const bf16x8*)(bp + (size_t)t * 16 * K + ks * 32);
            acc[t] = __builtin_amdgcn_mfma_f32_16x16x32_bf16(afrag[ks], bf, acc[t], 0, 0, 0);
        }
    }

    // ---- epilogue: C/D layout col=lane&15, row=quad*4+reg ----
    unsigned short* my = &cst[wave * 16 * PADW];
    #pragma unroll
    for (int t = 0; t < NT; ++t) {
        const float bb = bias[t * 16 + l16];
        #pragma unroll
        for (int r = 0; r < 4; ++r)
            my[(quad * 4 + r) * PADW + t * 16 + l16] = f2bf(acc[t][r] + bb);
    }
    __syncthreads();
    constexpr int CH = NCOLS / 8;          // 16B chunks per row
    #pragma unroll
    for (int i = 0; i < CH / 4; ++i) {
        int id = i * 64 + lane;
        int r  = id / CH, cc = id % CH;
        int grow = blockIdx.x * 64 + wave * 16 + r;
        if (grow < M)
            *(uint4*)&C[(size_t)grow * NCOLS + cc * 8] =
                *(const uint4*)&my[r * PADW + cc * 8];
    }
}

// ---------------------------------------------------------------------------
// Row-parallel CSR SpMM, bf16 table -> bf16 output, fp32 accumulate.
// 4-edge explicit batch: 4 independent 16B gathers in flight per lane,
// small register footprint (no shfl, no big arrays) -> high occupancy + MLP.
// ---------------------------------------------------------------------------
__device__ inline void fma8_bf16(float* acc, uint4 q, float v) {
    union { unsigned int i; float f; } t;
    #pragma unroll
    for (int p = 0; p < 4; ++p) {
        unsigned int w = (&q.x)[p];
        t.i = w << 16;          acc[2*p]   += v * t.f;
        t.i = w & 0xffff0000u;  acc[2*p+1] += v * t.f;
    }
}

template<int D, bool RELU>
__global__ __launch_bounds__(256) void spmm_bf16(const int* __restrict__ ptr,
                                                 const int* __restrict__ cols,
                                                 const float* __restrict__ vals,
                                                 const unsigned short* __restrict__ dense,
                                                 unsigned short* __restrict__ outm) {
    constexpr int LPR = D / 8;       // lanes per row
    constexpr int RPB = 256 / LPR;   // rows per block
    const int lane = threadIdx.x % LPR;
    const int row  = blockIdx.x * RPB + threadIdx.x / LPR;
    if (row >= NN) return;

    int e = ptr[row];
    const int e1 = ptr[row + 1];
    const size_t lo8 = (size_t)lane * 8;
    float acc[8] = {};

    for (; e + 4 <= e1; e += 4) {
        int   c0 = cols[e],   c1 = cols[e+1], c2 = cols[e+2], c3 = cols[e+3];
        float v0 = vals[e],   v1 = vals[e+1], v2 = vals[e+2], v3 = vals[e+3];
        uint4 q0 = *(const uint4*)&dense[(size_t)c0 * D + lo8];
        uint4 q1 = *(const uint4*)&dense[(size_t)c1 * D + lo8];
        uint4 q2 = *(const uint4*)&dense[(size_t)c2 * D + lo8];
        uint4 q3 = *(const uint4*)&dense[(size_t)c3 * D + lo8];
        fma8_bf16(acc, q0, v0);
        fma8_bf16(acc, q1, v1);
        fma8_bf16(acc, q2, v2);
        fma8_bf16(acc, q3, v3);
    }
    for (; e < e1; ++e) {
        int   c = cols[e];
        float v = vals[e];
        uint4 q = *(const uint4*)&dense[(size_t)c * D + lo8];
        fma8_bf16(acc, q, v);
    }

    if (RELU) {
        #pragma unroll
        for (int p = 0; p < 8; ++p) acc[p] = fmaxf(acc[p], 0.f);
    }
    uint4 o;
    #pragma unroll
    for (int p = 0; p < 4; ++p)
        (&o.x)[p] = (unsigned int)f2bf(acc[2*p]) | ((unsigned int)f2bf(acc[2*p+1]) << 16);
    *(uint4*)&outm[(size_t)row * D + lo8] = o;
}

// ---------------------------------------------------------------------------
// Decode: out[e] = dot(z[src[e]], z[dst[e]]), z bf16 [N,64]. 8 lanes/edge.
// ---------------------------------------------------------------------------
__global__ __launch_bounds__(256) void decode_dot_bf16(const unsigned short* __restrict__ z,
                                                       const int* __restrict__ ei,
                                                       float* __restrict__ outv) {
    const int lane = threadIdx.x & 7;
    const int e    = blockIdx.x * 32 + (threadIdx.x >> 3);
    if (e >= EQn) return;
    const int s = ei[e];
    const int d = ei[EQn + e];
    uint4 qa = *(const uint4*)&z[(size_t)s * 64 + lane * 8];
    uint4 qb = *(const uint4*)&z[(size_t)d * 64 + lane * 8];
    union { unsigned int i; float f; } ta, tb;
    float p = 0.f;
    #pragma unroll
    for (int k = 0; k < 4; ++k) {
        unsigned int wa = (&qa.x)[k], wb = (&qb.x)[k];
        ta.i = wa << 16;         tb.i = wb << 16;         p += ta.f * tb.f;
        ta.i = wa & 0xffff0000u; tb.i = wb & 0xffff0000u; p += ta.f * tb.f;
    }
    p += __shfl_xor(p, 1, 8);
    p += __shfl_xor(p, 2, 8);
    p += __shfl_xor(p, 4, 8);
    if (lane == 0) outv[e] = p;
}

// ---------------------------------------------------------------------------
extern "C" void kernel_launch(void* const* d_in, const int* in_sizes, int n_in,
                              void* d_out, int out_size, void* d_ws, size_t ws_size,
                              hipStream_t stream) {
    (void)in_sizes; (void)n_in; (void)out_size; (void)ws_size;

    const float* x        = (const float*)d_in[0];
    const int*   adj_rows = (const int*)  d_in[1];
    const int*   adj_cols = (const int*)  d_in[2];
    const float* adj_vals = (const float*)d_in[3];
    const int*   ei       = (const int*)  d_in[4];   // [2, EQ]
    const float* W1       = (const float*)d_in[5];
    const float* b1       = (const float*)d_in[6];
    const float* W2       = (const float*)d_in[7];
    const float* b2       = (const float*)d_in[8];
    float* out = (float*)d_out;

    // workspace: row_ptr | W1t | W2t | slotA bf16 [N,128] | slotB bf16 [N,128]
    char* ws = (char*)d_ws;
    int* row_ptr = (int*)ws;
    size_t off = ((size_t)(NN + 1) * sizeof(int) + 511) & ~(size_t)511;
    unsigned short* W1t = (unsigned short*)(ws + off);              // 64 KB
    unsigned short* W2t = W1t + (size_t)HIDF * INF_;                // 16 KB
    unsigned short* slotA = W2t + (size_t)OUTF * HIDF;
    slotA = (unsigned short*)(((size_t)slotA + 511) & ~(size_t)511);
    unsigned short* slotB = slotA + (size_t)NN * HIDF;

    build_row_ptr<<<(NN + 256) / 256, 256, 0, stream>>>(adj_rows, row_ptr);
    convert_weights<<<(INF_ * HIDF + 255) / 256, 256, 0, stream>>>(W1, W2, W1t, W2t);

    // h0 = x @ W1 + b1  -> slotA bf16 [N,128]
    gemm_direct<INF_, HIDF, false><<<(NN + 63) / 64, 256, 0, stream>>>(
        x, W1t, b1, slotA, NN);

    // h = relu(spmm(h0)) -> slotB bf16 [N,128]
    spmm_bf16<HIDF, true><<<(NN + 15) / 16, 256, 0, stream>>>(
        row_ptr, adj_cols, adj_vals, slotA, slotB);

    // z0 = h @ W2 + b2 -> slotA bf16 [N,64]  (A is bf16)
    gemm_direct<HIDF, OUTF, true><<<(NN + 63) / 64, 256, 0, stream>>>(
        slotB, W2t, b2, slotA, NN);

    // z = spmm(z0) -> slotB bf16 [N,64]
    spmm_bf16<OUTF, false><<<(NN + 31) / 32, 256, 0, stream>>>(
        row_ptr, adj_cols, adj_vals, slotA, slotB);

    // out[e] = dot(z[src], z[dst])
    decode_dot_bf16<<<EQn / 32, 256, 0, stream>>>(slotB, ei, out);
}